// Round 7
// baseline (1198.415 us; speedup 1.0000x reference)
//
#include <hip/hip_runtime.h>
#include <hip/hip_bf16.h>
#include <math.h>

typedef __hip_bfloat16 bf16;
typedef __attribute__((ext_vector_type(8))) short bf16x8;   // 8 bf16 = 4 VGPRs (guide §3)
typedef __attribute__((ext_vector_type(4))) float f32x4;

#define CDIM 768
#define HDIM 64
#define NHEAD 12
#define TSEQ 1024
#define MROWS 4096   // B*T
#define HID 3072
#define QKVN 2304    // 3*CDIM

__device__ inline void gld16(const void* g, void* l) {
  __builtin_amdgcn_global_load_lds((const __attribute__((address_space(1))) void*)g,
                                   (__attribute__((address_space(3))) void*)l, 16, 0, 0);
}

// ---------- all 6 weight transposes of one layer + qkv bias concat, ONE dispatch ----------
__global__ void k_transall(const float* __restrict__ Wq, const float* __restrict__ Wk,
                           const float* __restrict__ Wv, const float* __restrict__ Wp,
                           const float* __restrict__ W1, const float* __restrict__ W2,
                           const float* __restrict__ bq, const float* __restrict__ bk,
                           const float* __restrict__ bv,
                           bf16* __restrict__ wqkv, bf16* __restrict__ wtp,
                           bf16* __restrict__ wt1, bf16* __restrict__ wt2,
                           float* __restrict__ bqkv) {
  __shared__ float t[32][33];
  int blk = blockIdx.x;
  if (blk >= 6912) {           // 9 trailing blocks: concat q,k,v biases into [2304]
    int i = (blk - 6912) * 256 + threadIdx.y * 32 + threadIdx.x;
    if (i < QKVN) bqkv[i] = (i < CDIM) ? bq[i] : (i < 2 * CDIM) ? bk[i - CDIM] : bv[i - 2 * CDIM];
    return;
  }
  const float* src; bf16* dst; int K, N, n0, k0;
  if (blk < 1728) {            // Wq|Wk|Wv: 3 x 576 blocks of 768x768
    int w = blk / 576, id = blk % 576;
    src = (w == 0) ? Wq : (w == 1) ? Wk : Wv;
    dst = wqkv + (size_t)w * CDIM * CDIM;
    K = CDIM; N = CDIM;
    n0 = (id % 24) * 32; k0 = (id / 24) * 32;
  } else if (blk < 2304) {     // Wp
    int id = blk - 1728;
    src = Wp; dst = wtp; K = CDIM; N = CDIM;
    n0 = (id % 24) * 32; k0 = (id / 24) * 32;
  } else if (blk < 4608) {     // W1: [768,3072]
    int id = blk - 2304;
    src = W1; dst = wt1; K = CDIM; N = HID;
    n0 = (id % 96) * 32; k0 = (id / 96) * 32;
  } else {                     // W2: [3072,768]
    int id = blk - 4608;
    src = W2; dst = wt2; K = HID; N = CDIM;
    n0 = (id % 24) * 32; k0 = (id / 24) * 32;
  }
  int c = threadIdx.x, ry = threadIdx.y;
  #pragma unroll
  for (int i = 0; i < 4; i++) {
    int r = ry + 8 * i;
    t[r][c] = src[(size_t)(k0 + r) * N + n0 + c];
  }
  __syncthreads();
  #pragma unroll
  for (int i = 0; i < 4; i++) {
    int r = ry + 8 * i;
    dst[(size_t)(n0 + r) * K + k0 + c] = __float2bfloat16(t[c][r]);
  }
}

// ---------- layernorm: h fp32 [4096,768] -> out bf16 ----------
__global__ __launch_bounds__(256) void k_ln(const float* __restrict__ h, const float* __restrict__ g,
                                            const float* __restrict__ b, bf16* __restrict__ out) {
  int row = blockIdx.x, tid = threadIdx.x;
  const float* hr = h + (size_t)row * CDIM;
  float x0 = hr[tid], x1 = hr[tid + 256], x2 = hr[tid + 512];
  float s = x0 + x1 + x2;
  float ss = x0 * x0 + x1 * x1 + x2 * x2;
  #pragma unroll
  for (int off = 32; off > 0; off >>= 1) {
    s  += __shfl_down(s, off, 64);
    ss += __shfl_down(ss, off, 64);
  }
  __shared__ float rs[4], rq[4];
  if ((tid & 63) == 0) { rs[tid >> 6] = s; rq[tid >> 6] = ss; }
  __syncthreads();
  s  = rs[0] + rs[1] + rs[2] + rs[3];
  ss = rq[0] + rq[1] + rq[2] + rq[3];
  float mu = s * (1.0f / CDIM);
  float var = ss * (1.0f / CDIM) - mu * mu;
  float rstd = rsqrtf(var + 1e-5f);
  bf16* orow = out + (size_t)row * CDIM;
  orow[tid]       = __float2bfloat16((x0 - mu) * rstd * g[tid]       + b[tid]);
  orow[tid + 256] = __float2bfloat16((x1 - mu) * rstd * g[tid + 256] + b[tid + 256]);
  orow[tid + 512] = __float2bfloat16((x2 - mu) * rstd * g[tid + 512] + b[tid + 512]);
}

// ---------- GEMM, 64x128 tile (concurrency-first): out = A[M,K] @ Bt[N,K]^T + bias ----------
// grid (M/64, N/128). Wave w owns rows [64*bx + 16w, +16), all 128 cols.
// EPI: 0 = bias -> bf16; 1 = bias + gelu -> bf16.
template <int EPI>
__global__ __launch_bounds__(256) void k_gemm(const bf16* __restrict__ A, const bf16* __restrict__ Bt,
                                              const float* __restrict__ bias,
                                              bf16* __restrict__ out, int M, int N, int K) {
  __shared__ __align__(16) bf16 As[64 * 32];
  __shared__ __align__(16) bf16 Bs[128 * 32];
  int tid = threadIdx.x;
  int m0 = blockIdx.x * 64, n0 = blockIdx.y * 128;
  int wave = tid >> 6, lane = tid & 63;
  int lrow = lane & 15, quad = lane >> 4;
  f32x4 zz = {0.f, 0.f, 0.f, 0.f};
  f32x4 acc[8];
  #pragma unroll
  for (int j = 0; j < 8; j++) acc[j] = zz;
  const bf16* Ag = A + (size_t)m0 * K;
  const bf16* Bg = Bt + (size_t)n0 * K;
  for (int k0 = 0; k0 < K; k0 += 32) {
    __syncthreads();
    {
      int row = tid >> 2, ko = (tid & 3) * 8;
      gld16(Ag + (size_t)row * K + k0 + ko, As + tid * 8);
    }
    #pragma unroll
    for (int i = 0; i < 2; i++) {
      int idx = i * 256 + tid;
      int row = idx >> 2, ko = (idx & 3) * 8;
      gld16(Bg + (size_t)row * K + k0 + ko, Bs + idx * 8);
    }
    __syncthreads();
    bf16x8 af = *(const bf16x8*)(As + (wave * 16 + lrow) * 32 + quad * 8);
    #pragma unroll
    for (int j = 0; j < 8; j++) {
      bf16x8 bfr = *(const bf16x8*)(Bs + (j * 16 + lrow) * 32 + quad * 8);
      acc[j] = __builtin_amdgcn_mfma_f32_16x16x32_bf16(af, bfr, acc[j], 0, 0, 0);
    }
  }
  // D row = quad*4 + r, col = lrow (verified C/D layout)
  #pragma unroll
  for (int j = 0; j < 8; j++) {
    int gc = n0 + j * 16 + lrow;
    float bval = bias[gc];
    #pragma unroll
    for (int r = 0; r < 4; r++) {
      int grow = m0 + wave * 16 + quad * 4 + r;
      float vv = acc[j][r] + bval;
      if (EPI == 1) vv = 0.5f * vv * (1.0f + erff(vv * 0.70710678118654752f));
      out[(size_t)grow * N + gc] = __float2bfloat16(vv);
    }
  }
}

// ---------- split-K GEMM, 64x128 tile: h[M,N] += A@Bt^T + bias (fp32 atomics) ----------
__global__ __launch_bounds__(256) void k_gemm_sk(const bf16* __restrict__ A, const bf16* __restrict__ Bt,
                                                 const float* __restrict__ bias,
                                                 float* __restrict__ h, int M, int N, int K) {
  __shared__ __align__(16) bf16 As[64 * 32];
  __shared__ __align__(16) bf16 Bs[128 * 32];
  int tid = threadIdx.x;
  int m0 = blockIdx.x * 64, n0 = blockIdx.y * 128;
  int kchunk = K / gridDim.z;
  int kb = blockIdx.z * kchunk;
  int wave = tid >> 6, lane = tid & 63;
  int lrow = lane & 15, quad = lane >> 4;
  f32x4 zz = {0.f, 0.f, 0.f, 0.f};
  f32x4 acc[8];
  #pragma unroll
  for (int j = 0; j < 8; j++) acc[j] = zz;
  const bf16* Ag = A + (size_t)m0 * K;
  const bf16* Bg = Bt + (size_t)n0 * K;
  for (int k0 = kb; k0 < kb + kchunk; k0 += 32) {
    __syncthreads();
    {
      int row = tid >> 2, ko = (tid & 3) * 8;
      gld16(Ag + (size_t)row * K + k0 + ko, As + tid * 8);
    }
    #pragma unroll
    for (int i = 0; i < 2; i++) {
      int idx = i * 256 + tid;
      int row = idx >> 2, ko = (idx & 3) * 8;
      gld16(Bg + (size_t)row * K + k0 + ko, Bs + idx * 8);
    }
    __syncthreads();
    bf16x8 af = *(const bf16x8*)(As + (wave * 16 + lrow) * 32 + quad * 8);
    #pragma unroll
    for (int j = 0; j < 8; j++) {
      bf16x8 bfr = *(const bf16x8*)(Bs + (j * 16 + lrow) * 32 + quad * 8);
      acc[j] = __builtin_amdgcn_mfma_f32_16x16x32_bf16(af, bfr, acc[j], 0, 0, 0);
    }
  }
  bool addb = (blockIdx.z == 0);
  #pragma unroll
  for (int j = 0; j < 8; j++) {
    int gc = n0 + j * 16 + lrow;
    float bval = addb ? bias[gc] : 0.f;
    #pragma unroll
    for (int r = 0; r < 4; r++) {
      int grow = m0 + wave * 16 + quad * 4 + r;
      unsafeAtomicAdd(&h[(size_t)grow * N + gc], acc[j][r] + bval);
    }
  }
}

// ---------- MFMA flash attention ----------
__global__ __launch_bounds__(256) void k_attn(const bf16* __restrict__ qkv, bf16* __restrict__ y) {
  int bh = blockIdx.x;
  int b = bh / NHEAD, hh = bh % NHEAD;
  int qc = blockIdx.y;
  int tid = threadIdx.x;
  int wave = tid >> 6, lane = tid & 63;
  int lrow = lane & 15, quad = lane >> 4;
  int q0 = qc * 64 + wave * 16;
  int qmod = q0 & 255;
  int qcmod = (qc * 64) & 255;

  const size_t rstride = QKVN;
  const bf16* qbase = qkv + (size_t)(b * TSEQ) * rstride + hh * HDIM;
  const bf16* kbase = qbase + CDIM;
  const bf16* vbase = qbase + 2 * CDIM;

  bf16x8 qf[2];
  #pragma unroll
  for (int kc = 0; kc < 2; kc++)
    qf[kc] = *(const bf16x8*)(qbase + (size_t)(q0 + lrow) * rstride + kc * 32 + quad * 8);

  f32x4 zz = {0.f, 0.f, 0.f, 0.f};
  f32x4 Oacc[4];
  #pragma unroll
  for (int j = 0; j < 4; j++) Oacc[j] = zz;
  float m[4] = {-1e30f, -1e30f, -1e30f, -1e30f};
  float l[4] = {0.f, 0.f, 0.f, 0.f};

  __shared__ __align__(16) bf16 Ks[32 * 64];
  __shared__ __align__(16) bf16 Vt[64 * 40];
  __shared__ __align__(16) bf16 Pl[4][16 * 32];

  for (int kt = 0; kt < 32; kt++) {
    int k0 = kt * 32;
    int kmod = k0 & 255;
    if (kmod > qcmod + 63) continue;
    __syncthreads();
    {
      int key = tid >> 3, d0 = (tid & 7) * 8;
      *(bf16x8*)(Ks + tid * 8) =
          *(const bf16x8*)(kbase + (size_t)(k0 + key) * rstride + d0);
      int vkey = tid & 31, vd0 = (tid >> 5) * 8;
      bf16x8 vv = *(const bf16x8*)(vbase + (size_t)(k0 + vkey) * rstride + vd0);
      const bf16* vp = (const bf16*)&vv;
      #pragma unroll
      for (int j = 0; j < 8; j++) Vt[(vd0 + j) * 40 + vkey] = vp[j];
    }
    __syncthreads();
    if (kmod > qmod + 15) continue;

    f32x4 s[2];
    s[0] = zz; s[1] = zz;
    #pragma unroll
    for (int sub = 0; sub < 2; sub++)
      #pragma unroll
      for (int kc = 0; kc < 2; kc++) {
        bf16x8 kf = *(const bf16x8*)(Ks + (sub * 16 + lrow) * 64 + kc * 32 + quad * 8);
        s[sub] = __builtin_amdgcn_mfma_f32_16x16x32_bf16(qf[kc], kf, s[sub], 0, 0, 0);
      }
    bool partial = (kmod + 31 > qmod);
    #pragma unroll
    for (int sub = 0; sub < 2; sub++)
      #pragma unroll
      for (int r = 0; r < 4; r++) {
        float sv = s[sub][r] * 0.125f;
        if (partial) {
          int krel = kmod + sub * 16 + lrow;
          int qrel = qmod + quad * 4 + r;
          if (krel > qrel) sv = -1e30f;
        }
        s[sub][r] = sv;
      }
    float pr0[4], pr1[4], alpha[4];
    #pragma unroll
    for (int r = 0; r < 4; r++) {
      float v = fmaxf(s[0][r], s[1][r]);
      v = fmaxf(v, __shfl_xor(v, 1, 64));
      v = fmaxf(v, __shfl_xor(v, 2, 64));
      v = fmaxf(v, __shfl_xor(v, 4, 64));
      v = fmaxf(v, __shfl_xor(v, 8, 64));
      float mnew = fmaxf(m[r], v);
      alpha[r] = __expf(m[r] - mnew);
      m[r] = mnew;
      pr0[r] = __expf(s[0][r] - mnew);
      pr1[r] = __expf(s[1][r] - mnew);
      float rsum = pr0[r] + pr1[r];
      rsum += __shfl_xor(rsum, 1, 64);
      rsum += __shfl_xor(rsum, 2, 64);
      rsum += __shfl_xor(rsum, 4, 64);
      rsum += __shfl_xor(rsum, 8, 64);
      l[r] = l[r] * alpha[r] + rsum;
    }
    #pragma unroll
    for (int j = 0; j < 4; j++)
      #pragma unroll
      for (int r = 0; r < 4; r++) Oacc[j][r] *= alpha[r];
    bf16* Pw = (bf16*)Pl[wave];
    #pragma unroll
    for (int r = 0; r < 4; r++) {
      Pw[(quad * 4 + r) * 32 + lrow]      = __float2bfloat16(pr0[r]);
      Pw[(quad * 4 + r) * 32 + 16 + lrow] = __float2bfloat16(pr1[r]);
    }
    bf16x8 pf = *(const bf16x8*)(Pw + lrow * 32 + quad * 8);
    #pragma unroll
    for (int j = 0; j < 4; j++) {
      bf16x8 vf = *(const bf16x8*)(Vt + (j * 16 + lrow) * 40 + quad * 8);
      Oacc[j] = __builtin_amdgcn_mfma_f32_16x16x32_bf16(pf, vf, Oacc[j], 0, 0, 0);
    }
  }
  #pragma unroll
  for (int r = 0; r < 4; r++) {
    float inv = 1.0f / l[r];
    bf16* yp = y + (size_t)(b * TSEQ + q0 + quad * 4 + r) * CDIM + hh * HDIM;
    #pragma unroll
    for (int j = 0; j < 4; j++)
      yp[j * 16 + lrow] = __float2bfloat16(Oacc[j][r] * inv);
  }
}

extern "C" void kernel_launch(void* const* d_in, const int* in_sizes, int n_in,
                              void* d_out, int out_size, void* d_ws, size_t ws_size,
                              hipStream_t stream) {
  const float* x    = (const float*)d_in[0];
  const float* ln1g = (const float*)d_in[1];
  const float* ln1b = (const float*)d_in[2];
  const float* Wq   = (const float*)d_in[3];
  const float* bq   = (const float*)d_in[4];
  const float* Wk   = (const float*)d_in[5];
  const float* bk   = (const float*)d_in[6];
  const float* Wv   = (const float*)d_in[7];
  const float* bv   = (const float*)d_in[8];
  const float* Wp   = (const float*)d_in[9];
  const float* bp   = (const float*)d_in[10];
  const float* ln2g = (const float*)d_in[11];
  const float* ln2b = (const float*)d_in[12];
  const float* W1   = (const float*)d_in[13];
  const float* b1   = (const float*)d_in[14];
  const float* W2   = (const float*)d_in[15];
  const float* b2   = (const float*)d_in[16];

  char* ws = (char*)d_ws;
  size_t off = 0;
  float* h    = (float*)(ws + off); off += (size_t)MROWS * CDIM * 4;
  bf16* a     = (bf16*)(ws + off);  off += (size_t)MROWS * CDIM * 2;
  bf16* qkvb  = (bf16*)(ws + off);  off += (size_t)MROWS * QKVN * 2;
  bf16* yb    = (bf16*)(ws + off);  off += (size_t)MROWS * CDIM * 2;
  bf16* m1    = qkvb;  // alias: MLP hidden [4096,3072] overlays qkvb+yb (both dead by then)
  bf16* wqkv  = (bf16*)(ws + off);  off += (size_t)QKVN * CDIM * 2;
  bf16* wtp   = (bf16*)(ws + off);  off += (size_t)CDIM * CDIM * 2;
  bf16* wt1   = (bf16*)(ws + off);  off += (size_t)CDIM * HID * 2;
  bf16* wt2   = (bf16*)(ws + off);  off += (size_t)CDIM * HID * 2;
  float* bqkv = (float*)(ws + off); off += (size_t)QKVN * 4;

  int n = MROWS * CDIM;
  hipMemcpyAsync(h, x, (size_t)n * sizeof(float), hipMemcpyDeviceToDevice, stream);

  for (int l = 0; l < 4; l++) {
    const float* Wql = Wq + (size_t)l * CDIM * CDIM;
    const float* Wkl = Wk + (size_t)l * CDIM * CDIM;
    const float* Wvl = Wv + (size_t)l * CDIM * CDIM;
    const float* Wpl = Wp + (size_t)l * CDIM * CDIM;
    const float* W1l = W1 + (size_t)l * CDIM * HID;
    const float* W2l = W2 + (size_t)l * HID * CDIM;

    k_transall<<<dim3(6921), dim3(32, 8), 0, stream>>>(Wql, Wkl, Wvl, Wpl, W1l, W2l,
                                                       bq + l * CDIM, bk + l * CDIM, bv + l * CDIM,
                                                       wqkv, wtp, wt1, wt2, bqkv);

    k_ln<<<dim3(MROWS), dim3(256), 0, stream>>>(h, ln1g + l * CDIM, ln1b + l * CDIM, a);

    // QKV: 1152 blocks (4.5/CU)
    k_gemm<0><<<dim3(64, 18), dim3(256), 0, stream>>>(a, wqkv, bqkv, qkvb, MROWS, QKVN, CDIM);

    k_attn<<<dim3(4 * NHEAD, 16), dim3(256), 0, stream>>>(qkvb, yb);

    // attn-proj: h += yb @ wtp^T + bp   (1536 blocks, 6/CU)
    k_gemm_sk<<<dim3(64, 6, 4), dim3(256), 0, stream>>>(yb, wtp, bp + l * CDIM, h, MROWS, CDIM, CDIM);

    k_ln<<<dim3(MROWS), dim3(256), 0, stream>>>(h, ln2g + l * CDIM, ln2b + l * CDIM, a);

    // MLP1: 1536 blocks (6/CU)
    k_gemm<1><<<dim3(64, 24), dim3(256), 0, stream>>>(a, wt1, b1 + (size_t)l * HID, m1, MROWS, HID, CDIM);

    // MLP2: h += m1 @ wt2^T + b2   (1536 blocks, 6/CU)
    k_gemm_sk<<<dim3(64, 6, 4), dim3(256), 0, stream>>>(m1, wt2, b2 + l * CDIM, h, MROWS, CDIM, HID);
  }

  hipMemcpyAsync(d_out, h, (size_t)n * sizeof(float), hipMemcpyDeviceToDevice, stream);
}

// Round 8
// 1055.523 us; speedup vs baseline: 1.1354x; 1.1354x over previous
//
#include <hip/hip_runtime.h>
#include <hip/hip_bf16.h>
#include <math.h>

typedef __hip_bfloat16 bf16;
typedef __attribute__((ext_vector_type(8))) short bf16x8;   // 8 bf16 = 4 VGPRs
typedef __attribute__((ext_vector_type(4))) float f32x4;

#define CDIM 768
#define HDIM 64
#define NHEAD 12
#define TSEQ 1024
#define MROWS 4096   // B*T
#define HID 3072
#define QKVN 2304    // 3*CDIM

__device__ inline void gld16(const void* g, void* l) {
  __builtin_amdgcn_global_load_lds((const __attribute__((address_space(1))) void*)g,
                                   (__attribute__((address_space(3))) void*)l, 16, 0, 0);
}

// ---------- all 6 weight transposes of one layer + qkv bias concat, ONE dispatch ----------
__global__ void k_transall(const float* __restrict__ Wq, const float* __restrict__ Wk,
                           const float* __restrict__ Wv, const float* __restrict__ Wp,
                           const float* __restrict__ W1, const float* __restrict__ W2,
                           const float* __restrict__ bq, const float* __restrict__ bk,
                           const float* __restrict__ bv,
                           bf16* __restrict__ wqkv, bf16* __restrict__ wtp,
                           bf16* __restrict__ wt1, bf16* __restrict__ wt2,
                           float* __restrict__ bqkv) {
  __shared__ float t[32][33];
  int blk = blockIdx.x;
  if (blk >= 6912) {           // 9 trailing blocks: concat q,k,v biases into [2304]
    int i = (blk - 6912) * 256 + threadIdx.y * 32 + threadIdx.x;
    if (i < QKVN) bqkv[i] = (i < CDIM) ? bq[i] : (i < 2 * CDIM) ? bk[i - CDIM] : bv[i - 2 * CDIM];
    return;
  }
  const float* src; bf16* dst; int K, N, n0, k0;
  if (blk < 1728) {            // Wq|Wk|Wv
    int w = blk / 576, id = blk % 576;
    src = (w == 0) ? Wq : (w == 1) ? Wk : Wv;
    dst = wqkv + (size_t)w * CDIM * CDIM;
    K = CDIM; N = CDIM;
    n0 = (id % 24) * 32; k0 = (id / 24) * 32;
  } else if (blk < 2304) {     // Wp
    int id = blk - 1728;
    src = Wp; dst = wtp; K = CDIM; N = CDIM;
    n0 = (id % 24) * 32; k0 = (id / 24) * 32;
  } else if (blk < 4608) {     // W1: [768,3072]
    int id = blk - 2304;
    src = W1; dst = wt1; K = CDIM; N = HID;
    n0 = (id % 96) * 32; k0 = (id / 96) * 32;
  } else {                     // W2: [3072,768]
    int id = blk - 4608;
    src = W2; dst = wt2; K = HID; N = CDIM;
    n0 = (id % 24) * 32; k0 = (id / 24) * 32;
  }
  int c = threadIdx.x, ry = threadIdx.y;
  #pragma unroll
  for (int i = 0; i < 4; i++) {
    int r = ry + 8 * i;
    t[r][c] = src[(size_t)(k0 + r) * N + n0 + c];
  }
  __syncthreads();
  #pragma unroll
  for (int i = 0; i < 4; i++) {
    int r = ry + 8 * i;
    dst[(size_t)(n0 + r) * K + k0 + c] = __float2bfloat16(t[c][r]);
  }
}

// ---------- layernorm ----------
__global__ __launch_bounds__(256) void k_ln(const float* __restrict__ h, const float* __restrict__ g,
                                            const float* __restrict__ b, bf16* __restrict__ out) {
  int row = blockIdx.x, tid = threadIdx.x;
  const float* hr = h + (size_t)row * CDIM;
  float x0 = hr[tid], x1 = hr[tid + 256], x2 = hr[tid + 512];
  float s = x0 + x1 + x2;
  float ss = x0 * x0 + x1 * x1 + x2 * x2;
  #pragma unroll
  for (int off = 32; off > 0; off >>= 1) {
    s  += __shfl_down(s, off, 64);
    ss += __shfl_down(ss, off, 64);
  }
  __shared__ float rs[4], rq[4];
  if ((tid & 63) == 0) { rs[tid >> 6] = s; rq[tid >> 6] = ss; }
  __syncthreads();
  s  = rs[0] + rs[1] + rs[2] + rs[3];
  ss = rq[0] + rq[1] + rq[2] + rq[3];
  float mu = s * (1.0f / CDIM);
  float var = ss * (1.0f / CDIM) - mu * mu;
  float rstd = rsqrtf(var + 1e-5f);
  bf16* orow = out + (size_t)row * CDIM;
  orow[tid]       = __float2bfloat16((x0 - mu) * rstd * g[tid]       + b[tid]);
  orow[tid + 256] = __float2bfloat16((x1 - mu) * rstd * g[tid + 256] + b[tid + 256]);
  orow[tid + 512] = __float2bfloat16((x2 - mu) * rstd * g[tid + 512] + b[tid + 512]);
}

// ===== XOR-swizzled LDS tile helpers =====
// Tile [rows][64 bf16] = [rows][8 chunks of 8]. Row r, chunk c stored at slot c^(r&7).
// Staging (gld16, lane-consecutive dests): lane slot idx -> global chunk (idx&7)^((idx>>3)&7).
// Fragment read of logical chunk g from row r: LDS offset r*64 + (g^(r&7))*8. 2-way banks = free.

// ---------- GEMM, 64x128 tile, BK=64, swizzled: out = A[M,K] @ Bt[N,K]^T + bias ----------
// EPI: 0 = bias -> bf16; 1 = bias + gelu -> bf16.
template <int EPI>
__global__ __launch_bounds__(256) void k_gemm(const bf16* __restrict__ A, const bf16* __restrict__ Bt,
                                              const float* __restrict__ bias,
                                              bf16* __restrict__ out, int M, int N, int K) {
  __shared__ __align__(16) bf16 As[64 * 64];
  __shared__ __align__(16) bf16 Bs[128 * 64];
  int tid = threadIdx.x;
  int m0 = blockIdx.x * 64, n0 = blockIdx.y * 128;
  int wave = tid >> 6, lane = tid & 63;
  int lrow = lane & 15, quad = lane >> 4;
  int sw = lrow & 7;
  f32x4 zz = {0.f, 0.f, 0.f, 0.f};
  f32x4 acc[8];
  #pragma unroll
  for (int j = 0; j < 8; j++) acc[j] = zz;
  const bf16* Ag = A + (size_t)m0 * K;
  const bf16* Bg = Bt + (size_t)n0 * K;
  for (int k0 = 0; k0 < K; k0 += 64) {
    __syncthreads();
    #pragma unroll
    for (int i = 0; i < 2; i++) {      // A: 64 rows x 8 chunks = 512 slots
      int idx = i * 256 + tid;
      int row = idx >> 3, c = idx & 7;
      gld16(Ag + (size_t)row * K + k0 + ((c ^ (row & 7)) * 8), As + idx * 8);
    }
    #pragma unroll
    for (int i = 0; i < 4; i++) {      // B: 128 rows x 8 chunks = 1024 slots
      int idx = i * 256 + tid;
      int row = idx >> 3, c = idx & 7;
      gld16(Bg + (size_t)row * K + k0 + ((c ^ (row & 7)) * 8), Bs + idx * 8);
    }
    __syncthreads();
    #pragma unroll
    for (int kc = 0; kc < 2; kc++) {
      int g = kc * 4 + quad;
      bf16x8 af = *(const bf16x8*)(As + (wave * 16 + lrow) * 64 + ((g ^ sw) * 8));
      #pragma unroll
      for (int j = 0; j < 8; j++) {
        bf16x8 bfr = *(const bf16x8*)(Bs + (j * 16 + lrow) * 64 + ((g ^ sw) * 8));
        acc[j] = __builtin_amdgcn_mfma_f32_16x16x32_bf16(af, bfr, acc[j], 0, 0, 0);
      }
    }
  }
  #pragma unroll
  for (int j = 0; j < 8; j++) {
    int gc = n0 + j * 16 + lrow;
    float bval = bias[gc];
    #pragma unroll
    for (int r = 0; r < 4; r++) {
      int grow = m0 + wave * 16 + quad * 4 + r;
      float vv = acc[j][r] + bval;
      if (EPI == 1) vv = 0.5f * vv * (1.0f + erff(vv * 0.70710678118654752f));
      out[(size_t)grow * N + gc] = __float2bfloat16(vv);
    }
  }
}

// ---------- split-K GEMM, 64x128, BK=64, swizzled: h += A@Bt^T + bias (fp32 atomics) ----------
__global__ __launch_bounds__(256) void k_gemm_sk(const bf16* __restrict__ A, const bf16* __restrict__ Bt,
                                                 const float* __restrict__ bias,
                                                 float* __restrict__ h, int M, int N, int K) {
  __shared__ __align__(16) bf16 As[64 * 64];
  __shared__ __align__(16) bf16 Bs[128 * 64];
  int tid = threadIdx.x;
  int m0 = blockIdx.x * 64, n0 = blockIdx.y * 128;
  int kchunk = K / gridDim.z;
  int kb = blockIdx.z * kchunk;
  int wave = tid >> 6, lane = tid & 63;
  int lrow = lane & 15, quad = lane >> 4;
  int sw = lrow & 7;
  f32x4 zz = {0.f, 0.f, 0.f, 0.f};
  f32x4 acc[8];
  #pragma unroll
  for (int j = 0; j < 8; j++) acc[j] = zz;
  const bf16* Ag = A + (size_t)m0 * K;
  const bf16* Bg = Bt + (size_t)n0 * K;
  for (int k0 = kb; k0 < kb + kchunk; k0 += 64) {
    __syncthreads();
    #pragma unroll
    for (int i = 0; i < 2; i++) {
      int idx = i * 256 + tid;
      int row = idx >> 3, c = idx & 7;
      gld16(Ag + (size_t)row * K + k0 + ((c ^ (row & 7)) * 8), As + idx * 8);
    }
    #pragma unroll
    for (int i = 0; i < 4; i++) {
      int idx = i * 256 + tid;
      int row = idx >> 3, c = idx & 7;
      gld16(Bg + (size_t)row * K + k0 + ((c ^ (row & 7)) * 8), Bs + idx * 8);
    }
    __syncthreads();
    #pragma unroll
    for (int kc = 0; kc < 2; kc++) {
      int g = kc * 4 + quad;
      bf16x8 af = *(const bf16x8*)(As + (wave * 16 + lrow) * 64 + ((g ^ sw) * 8));
      #pragma unroll
      for (int j = 0; j < 8; j++) {
        bf16x8 bfr = *(const bf16x8*)(Bs + (j * 16 + lrow) * 64 + ((g ^ sw) * 8));
        acc[j] = __builtin_amdgcn_mfma_f32_16x16x32_bf16(af, bfr, acc[j], 0, 0, 0);
      }
    }
  }
  bool addb = (blockIdx.z == 0);
  #pragma unroll
  for (int j = 0; j < 8; j++) {
    int gc = n0 + j * 16 + lrow;
    float bval = addb ? bias[gc] : 0.f;
    #pragma unroll
    for (int r = 0; r < 4; r++) {
      int grow = m0 + wave * 16 + quad * 4 + r;
      unsafeAtomicAdd(&h[(size_t)grow * N + gc], acc[j][r] + bval);
    }
  }
}

// ---------- MFMA flash attention, K-tile = 64, swizzled Ks/P ----------
// grid (48, 16); block 256 = 4 waves; wave owns 16 q rows. mask: (k%256) <= (q%256).
__global__ __launch_bounds__(256) void k_attn(const bf16* __restrict__ qkv, bf16* __restrict__ y) {
  int bh = blockIdx.x;
  int b = bh / NHEAD, hh = bh % NHEAD;
  int qc = blockIdx.y;
  int tid = threadIdx.x;
  int wave = tid >> 6, lane = tid & 63;
  int lrow = lane & 15, quad = lane >> 4;
  int sw = lrow & 7;
  int q0 = qc * 64 + wave * 16;
  int qmod = q0 & 255;
  int qcmod = (qc * 64) & 255;

  const size_t rstride = QKVN;
  const bf16* qbase = qkv + (size_t)(b * TSEQ) * rstride + hh * HDIM;
  const bf16* kbase = qbase + CDIM;
  const bf16* vbase = qbase + 2 * CDIM;

  bf16x8 qf[2];
  #pragma unroll
  for (int kc = 0; kc < 2; kc++)
    qf[kc] = *(const bf16x8*)(qbase + (size_t)(q0 + lrow) * rstride + kc * 32 + quad * 8);

  f32x4 zz = {0.f, 0.f, 0.f, 0.f};
  f32x4 Oacc[4];
  #pragma unroll
  for (int j = 0; j < 4; j++) Oacc[j] = zz;
  float m[4] = {-1e30f, -1e30f, -1e30f, -1e30f};
  float l[4] = {0.f, 0.f, 0.f, 0.f};

  __shared__ __align__(16) bf16 Ks[64 * 64];       // [key][d], XOR-swizzled chunks
  __shared__ __align__(16) bf16 Vt[64 * 72];       // [d][key], pad 72
  __shared__ __align__(16) bf16 Pl[4][16 * 64];    // per-wave P, XOR-swizzled chunks

  for (int kt = 0; kt < 16; kt++) {
    int k0 = kt * 64;
    int kmod = k0 & 255;
    if (kmod > qcmod + 63) continue;       // block-uniform skip
    __syncthreads();
    #pragma unroll
    for (int i = 0; i < 2; i++) {
      int idx = i * 256 + tid;
      // K: 64 keys x 8 chunks, swizzled
      int key = idx >> 3, c = idx & 7;
      gld16(kbase + (size_t)(k0 + key) * rstride + ((c ^ (key & 7)) * 8), Ks + idx * 8);
      // V transposed: vkey = idx&63, vd0 = (idx>>6)*8
      int vkey = idx & 63, vd0 = (idx >> 6) * 8;
      bf16x8 vv = *(const bf16x8*)(vbase + (size_t)(k0 + vkey) * rstride + vd0);
      const bf16* vp = (const bf16*)&vv;
      #pragma unroll
      for (int j = 0; j < 8; j++) Vt[(vd0 + j) * 72 + vkey] = vp[j];
    }
    __syncthreads();
    if (kmod > qmod + 15) continue;        // wave-uniform skip

    // S = Q @ K^T: 4 key-subtiles of 16
    f32x4 s[4];
    #pragma unroll
    for (int sub = 0; sub < 4; sub++) {
      s[sub] = zz;
      #pragma unroll
      for (int kc = 0; kc < 2; kc++) {
        int g = kc * 4 + quad;
        bf16x8 kf = *(const bf16x8*)(Ks + (sub * 16 + lrow) * 64 + ((g ^ sw) * 8));
        s[sub] = __builtin_amdgcn_mfma_f32_16x16x32_bf16(qf[kc], kf, s[sub], 0, 0, 0);
      }
    }
    bool partial = (kmod + 63 > qmod);
    #pragma unroll
    for (int sub = 0; sub < 4; sub++)
      #pragma unroll
      for (int r = 0; r < 4; r++) {
        float sv = s[sub][r] * 0.125f;     // 1/sqrt(64)
        if (partial) {
          int krel = kmod + sub * 16 + lrow;
          int qrel = qmod + quad * 4 + r;
          if (krel > qrel) sv = -1e30f;
        }
        s[sub][r] = sv;
      }
    // online softmax (rows live on the quad's 16 lanes)
    float pr[4][4], alpha[4];
    #pragma unroll
    for (int r = 0; r < 4; r++) {
      float v = fmaxf(fmaxf(s[0][r], s[1][r]), fmaxf(s[2][r], s[3][r]));
      v = fmaxf(v, __shfl_xor(v, 1, 64));
      v = fmaxf(v, __shfl_xor(v, 2, 64));
      v = fmaxf(v, __shfl_xor(v, 4, 64));
      v = fmaxf(v, __shfl_xor(v, 8, 64));
      float mnew = fmaxf(m[r], v);
      alpha[r] = __expf(m[r] - mnew);
      m[r] = mnew;
      float rsum = 0.f;
      #pragma unroll
      for (int sub = 0; sub < 4; sub++) {
        pr[sub][r] = __expf(s[sub][r] - mnew);
        rsum += pr[sub][r];
      }
      rsum += __shfl_xor(rsum, 1, 64);
      rsum += __shfl_xor(rsum, 2, 64);
      rsum += __shfl_xor(rsum, 4, 64);
      rsum += __shfl_xor(rsum, 8, 64);
      l[r] = l[r] * alpha[r] + rsum;
    }
    #pragma unroll
    for (int j = 0; j < 4; j++)
      #pragma unroll
      for (int r = 0; r < 4; r++) Oacc[j][r] *= alpha[r];
    // P: C-layout -> LDS (swizzled chunks) -> A-layout
    bf16* Pw = (bf16*)Pl[wave];
    #pragma unroll
    for (int sub = 0; sub < 4; sub++) {
      int cc = sub * 2 + (lrow >> 3);      // chunk of key index sub*16+lrow
      int e = lrow & 7;
      #pragma unroll
      for (int r = 0; r < 4; r++) {
        int mm = quad * 4 + r;
        Pw[mm * 64 + ((cc ^ (mm & 7)) * 8) + e] = __float2bfloat16(pr[sub][r]);
      }
    }
    bf16x8 pf[2];
    #pragma unroll
    for (int kc = 0; kc < 2; kc++) {
      int g = kc * 4 + quad;
      pf[kc] = *(const bf16x8*)(Pw + lrow * 64 + ((g ^ sw) * 8));
    }
    #pragma unroll
    for (int j = 0; j < 4; j++)
      #pragma unroll
      for (int kc = 0; kc < 2; kc++) {
        bf16x8 vf = *(const bf16x8*)(Vt + (j * 16 + lrow) * 72 + kc * 32 + quad * 8);
        Oacc[j] = __builtin_amdgcn_mfma_f32_16x16x32_bf16(pf[kc], vf, Oacc[j], 0, 0, 0);
      }
  }
  #pragma unroll
  for (int r = 0; r < 4; r++) {
    float inv = 1.0f / l[r];
    bf16* yp = y + (size_t)(b * TSEQ + q0 + quad * 4 + r) * CDIM + hh * HDIM;
    #pragma unroll
    for (int j = 0; j < 4; j++)
      yp[j * 16 + lrow] = __float2bfloat16(Oacc[j][r] * inv);
  }
}

extern "C" void kernel_launch(void* const* d_in, const int* in_sizes, int n_in,
                              void* d_out, int out_size, void* d_ws, size_t ws_size,
                              hipStream_t stream) {
  const float* x    = (const float*)d_in[0];
  const float* ln1g = (const float*)d_in[1];
  const float* ln1b = (const float*)d_in[2];
  const float* Wq   = (const float*)d_in[3];
  const float* bq   = (const float*)d_in[4];
  const float* Wk   = (const float*)d_in[5];
  const float* bk   = (const float*)d_in[6];
  const float* Wv   = (const float*)d_in[7];
  const float* bv   = (const float*)d_in[8];
  const float* Wp   = (const float*)d_in[9];
  const float* bp   = (const float*)d_in[10];
  const float* ln2g = (const float*)d_in[11];
  const float* ln2b = (const float*)d_in[12];
  const float* W1   = (const float*)d_in[13];
  const float* b1   = (const float*)d_in[14];
  const float* W2   = (const float*)d_in[15];
  const float* b2   = (const float*)d_in[16];

  char* ws = (char*)d_ws;
  size_t off = 0;
  float* h    = (float*)(ws + off); off += (size_t)MROWS * CDIM * 4;
  bf16* a     = (bf16*)(ws + off);  off += (size_t)MROWS * CDIM * 2;
  bf16* qkvb  = (bf16*)(ws + off);  off += (size_t)MROWS * QKVN * 2;
  bf16* yb    = (bf16*)(ws + off);  off += (size_t)MROWS * CDIM * 2;
  bf16* m1    = qkvb;  // alias: MLP hidden [4096,3072] overlays qkvb+yb (both dead by then)
  bf16* wqkv  = (bf16*)(ws + off);  off += (size_t)QKVN * CDIM * 2;
  bf16* wtp   = (bf16*)(ws + off);  off += (size_t)CDIM * CDIM * 2;
  bf16* wt1   = (bf16*)(ws + off);  off += (size_t)CDIM * HID * 2;
  bf16* wt2   = (bf16*)(ws + off);  off += (size_t)CDIM * HID * 2;
  float* bqkv = (float*)(ws + off); off += (size_t)QKVN * 4;

  int n = MROWS * CDIM;
  hipMemcpyAsync(h, x, (size_t)n * sizeof(float), hipMemcpyDeviceToDevice, stream);

  for (int l = 0; l < 4; l++) {
    const float* Wql = Wq + (size_t)l * CDIM * CDIM;
    const float* Wkl = Wk + (size_t)l * CDIM * CDIM;
    const float* Wvl = Wv + (size_t)l * CDIM * CDIM;
    const float* Wpl = Wp + (size_t)l * CDIM * CDIM;
    const float* W1l = W1 + (size_t)l * CDIM * HID;
    const float* W2l = W2 + (size_t)l * HID * CDIM;

    k_transall<<<dim3(6921), dim3(32, 8), 0, stream>>>(Wql, Wkl, Wvl, Wpl, W1l, W2l,
                                                       bq + l * CDIM, bk + l * CDIM, bv + l * CDIM,
                                                       wqkv, wtp, wt1, wt2, bqkv);

    k_ln<<<dim3(MROWS), dim3(256), 0, stream>>>(h, ln1g + l * CDIM, ln1b + l * CDIM, a);

    k_gemm<0><<<dim3(64, 18), dim3(256), 0, stream>>>(a, wqkv, bqkv, qkvb, MROWS, QKVN, CDIM);

    k_attn<<<dim3(4 * NHEAD, 16), dim3(256), 0, stream>>>(qkvb, yb);

    k_gemm_sk<<<dim3(64, 6, 4), dim3(256), 0, stream>>>(yb, wtp, bp + l * CDIM, h, MROWS, CDIM, CDIM);

    k_ln<<<dim3(MROWS), dim3(256), 0, stream>>>(h, ln2g + l * CDIM, ln2b + l * CDIM, a);

    k_gemm<1><<<dim3(64, 24), dim3(256), 0, stream>>>(a, wt1, b1 + (size_t)l * HID, m1, MROWS, HID, CDIM);

    k_gemm_sk<<<dim3(64, 6, 4), dim3(256), 0, stream>>>(m1, wt2, b2 + l * CDIM, h, MROWS, CDIM, HID);
  }

  hipMemcpyAsync(d_out, h, (size_t)n * sizeof(float), hipMemcpyDeviceToDevice, stream);
}